// Round 4
// baseline (910.340 us; speedup 1.0000x reference)
//
#include <hip/hip_runtime.h>
#include <stdint.h>

#define BATCH 32
#define NANCH 25200
#define CH 85
#define NCLS 80
#define TOPK 512
#define CONF_THRE 0.7f
#define NMS_THRE 0.45f
#define CLS_OFF 4096.0f

typedef unsigned long long u64;
typedef unsigned int u32;

// ws layout (bytes):  (fill evidence: ws ~1 GB = 4x input, so 8.2 MB is safe)
//   [0, 6451200)          u64 list[32][25200]      compact (conf<<32 | ~anchor) keys
//   [6451200, +256)       u32 cnt[32]              per-image valid count
//   [6451456, +327680)    float nms[32][5][512]    x1,y1,x2,y2,area (class-offset)
//   [6779136, +393216)    float det[32][512][6]
//   [7172352, +2048)      u64 valid[32][8]
//   [7174400, +1048576)   u64 mask[32][512][8]
#define OFF_LIST  0
#define OFF_CNT   6451200
#define OFF_NMS   6451456
#define OFF_DET   6779136
#define OFF_VALID 7172352
#define OFF_MASK  7174400

// ---- k0: zero the per-image counters (workspace is poisoned, not zeroed) ----
__global__ __launch_bounds__(64) void zero_kernel(u32* __restrict__ cntG) {
    if (threadIdx.x < BATCH) cntG[threadIdx.x] = 0u;
}

// ---- k1 scan: wave-transposed compute, 16 lanes per anchor; per-block LDS
//      aggregation emits a per-image compact key list (1 atomic / 16 anchors) ----
__global__ __launch_bounds__(256) void scan_kernel(const float* __restrict__ pred,
                                                   u64* __restrict__ listG,
                                                   u32* __restrict__ cntG) {
    __shared__ u32 sc[16];
    const int tid = threadIdx.x;
    const int lane = tid & 63;
    const int wv = tid >> 6;
    const int g = lane >> 4;          // anchor-in-wave 0..3
    const int l = lane & 15;          // lane-in-group
    const int a = blockIdx.x * 16 + wv * 4 + g;     // flat img*NANCH+anchor
    const size_t base = (size_t)a * CH;

    float m = -1.0f, obj = 0.0f;
    {   // p = l*4 .. l*4+3  (covers 0..63)
        const float4 q = *(const float4*)(pred + base + (l << 2));
        const int p = l << 2;
        if (p + 0 >= 5) m = fmaxf(m, q.x); else if (p + 0 == 4) obj = q.x;
        if (p + 1 >= 5) m = fmaxf(m, q.y); else if (p + 1 == 4) obj = q.y;
        if (p + 2 >= 5) m = fmaxf(m, q.z); else if (p + 2 == 4) obj = q.z;
        if (p + 3 >= 5) m = fmaxf(m, q.w); else if (p + 3 == 4) obj = q.w;
    }
    if (l < 5) {                      // p = 64 .. 83 (all classes)
        const float4 q = *(const float4*)(pred + base + 64 + (l << 2));
        m = fmaxf(fmaxf(m, fmaxf(q.x, q.y)), fmaxf(q.z, q.w));
    } else if (l == 5) {              // p = 84
        m = fmaxf(m, pred[base + 84]);
    }
    #pragma unroll
    for (int off = 1; off < 16; off <<= 1) m = fmaxf(m, __shfl_xor(m, off));
    const float ob = __shfl(obj, (lane & 48) + 1);  // lane g*16+1 holds p==4
    const float conf = ob * m;
    if (l == 0)
        sc[wv * 4 + g] = (conf >= CONF_THRE) ? __float_as_uint(conf) : 0u;
    __syncthreads();

    // wave 0, lanes 0..15: compact this block's <=16 valid anchors into the list
    if (tid < 16) {
        const u32 cc = sc[tid];
        const u64 mask = __ballot(cc != 0u);    // bits only in 0..15
        if (mask) {
            const u32 n = __popc((u32)mask);
            const u32 img = (u32)blockIdx.x / (NANCH / 16);   // 16 anchors all same image
            u32 bs = 0;
            if (tid == 0) bs = atomicAdd(&cntG[img], n);
            bs = __shfl(bs, 0);
            if (cc) {
                const u32 rnk = __popc((u32)mask & ((1u << tid) - 1u));
                const u32 anchor = (u32)(blockIdx.x * 16 + tid) - img * NANCH;
                listG[(size_t)img * NANCH + bs + rnk] =
                    ((u64)cc << 32) | (u64)(0xFFFFFFFFu - anchor);
            }
        }
    }
}

// ---- k2: hist + threshold + compact + rank sort + gather, all over the
//      per-image compact list (~8 iterations instead of 25 per pass) ----
__global__ __launch_bounds__(1024) void select_kernel(const float* __restrict__ pred,
                                                      const u64* __restrict__ listG,
                                                      const u32* __restrict__ cntG,
                                                      float* __restrict__ nmsG,
                                                      float* __restrict__ detG,
                                                      u64* __restrict__ validG) {
    __shared__ u64 sbuf[1024];
    __shared__ u64 sorted[1024];
    __shared__ u32 hist[256];
    __shared__ u32 wtot[4];
    __shared__ u32 s_cnt, s_pivot;
    __shared__ unsigned char val[TOPK];

    const int img = blockIdx.x;
    const int tid = threadIdx.x;
    const int lane = tid & 63;
    const int wv = tid >> 6;

    if (tid == 0) { s_cnt = 0u; s_pivot = 0u; }   // pivot 0 => T=0x3F000000 selects all valid
    if (tid < 256) hist[tid] = 0u;
    __syncthreads();

    const u32 cnt = cntG[img];                    // <= NANCH by construction
    const u64* keys = listG + (size_t)img * NANCH;

    // pass 1: 256-bin histogram of top-8 mantissa bits (valid bins 102..255)
    for (u32 i = tid; i < cnt; i += 1024) {
        const u32 c = (u32)(keys[i] >> 32);
        atomicAdd(&hist[(c >> 15) & 255u], 1u);
    }
    __syncthreads();

    // inclusive suffix scan over 256 bins (4 waves + cross-wave totals)
    u32 v = 0, s = 0;
    if (tid < 256) {
        v = hist[tid]; s = v;
        #pragma unroll
        for (int off = 1; off < 64; off <<= 1) {
            const u32 t = __shfl_down(s, off);
            if (lane + off < 64) s += t;
        }
        if (lane == 0) wtot[wv] = s;
    }
    __syncthreads();
    if (tid < 256) {
        u32 add = 0;
        for (int w2 = wv + 1; w2 < 4; ++w2) add += wtot[w2];
        const u32 sfull = s + add;        // count in bins >= tid
        const u32 snext = sfull - v;      // count in bins >  tid
        if (sfull >= TOPK && snext < TOPK) s_pivot = (u32)tid;
    }
    __syncthreads();
    const u32 T = 0x3F000000u | (s_pivot << 15);

    // pass 2 (L3-hot): compact keys with conf >= T (rank sort restores exact order)
    for (u32 i = tid; i < cnt; i += 1024) {
        const u64 k = keys[i];
        if ((u32)(k >> 32) >= T) {
            const u32 pos = atomicAdd(&s_cnt, 1u);
            if (pos < 1024u) sbuf[pos] = k;
        }
    }
    __syncthreads();
    const u32 mc = (s_cnt > 1024u) ? 1024u : s_cnt;

    // rank sort (keys unique by anchor): rank = #{key' > key}
    sorted[tid] = 0ull;
    u32 rank = 0; u64 my = 0ull;
    if (tid < (int)mc) {
        my = sbuf[tid];
        for (u32 i = 0; i < mc; ++i) rank += (sbuf[i] > my) ? 1u : 0u;
    }
    __syncthreads();
    if (tid < (int)mc && rank < 1024u) sorted[rank] = my;
    __syncthreads();

    // gather: 8 rows per wave via 8-lane groups; 4 sequential batches of 128 rows.
    // lane l covers classes {l, 8+l, ..., 72+l}; argmax first-max tie rule.
    const int g = lane >> 3;          // row-in-wave 0..7
    const int l = lane & 7;           // lane-in-group
    float* nb_ = nmsG + (size_t)img * (5 * TOPK);
    float* dt_ = detG + (size_t)img * (6 * TOPK);
    for (int pass = 0; pass < 4; ++pass) {
        const int r = pass * 128 + wv * 8 + g;
        const u64 key = sorted[r];
        const float conf = __uint_as_float((u32)(key >> 32));
        const bool okrow = conf >= CONF_THRE;
        float x1 = 0.f, y1 = 0.f, x2 = 0.f, y2 = 0.f, clsf = 0.f;
        if (okrow) {
            const u32 anchor = 0xFFFFFFFFu - (u32)(key & 0xFFFFFFFFull);
            const float* row = pred + ((size_t)img * NANCH + anchor) * CH;
            // 10 independent strided loads + box load, all issued together
            float vs[10];
            #pragma unroll
            for (int k = 0; k < 10; ++k) vs[k] = row[5 + l + 8 * k];
            float4 box;
            if (l == 0) box = *(const float4*)row;
            float vv = vs[0];
            int ci = l;
            #pragma unroll
            for (int k = 1; k < 10; ++k)
                if (vs[k] > vv) { vv = vs[k]; ci = 8 * k + l; }   // strict > keeps lowest idx
            // reduce within 8-lane group: larger value wins; tie -> lower class idx
            #pragma unroll
            for (int off = 4; off > 0; off >>= 1) {
                const float ov = __shfl_xor(vv, off);
                const int oi = __shfl_xor(ci, off);
                if (ov > vv || (ov == vv && oi < ci)) { vv = ov; ci = oi; }
            }
            if (l == 0) {
                const float hw = box.z * 0.5f, hh = box.w * 0.5f;
                x1 = box.x - hw; y1 = box.y - hh; x2 = box.x + hw; y2 = box.y + hh;
                clsf = (float)ci;
            }
        }
        if (l == 0) {
            const float off = clsf * CLS_OFF;
            const float X1 = x1 + off, Y1 = y1 + off, X2 = x2 + off, Y2 = y2 + off;
            nb_[0 * TOPK + r] = X1; nb_[1 * TOPK + r] = Y1;
            nb_[2 * TOPK + r] = X2; nb_[3 * TOPK + r] = Y2;
            nb_[4 * TOPK + r] = (X2 - X1) * (Y2 - Y1);
            dt_[r * 6 + 0] = x1; dt_[r * 6 + 1] = y1;
            dt_[r * 6 + 2] = x2; dt_[r * 6 + 3] = y2;
            dt_[r * 6 + 4] = okrow ? conf : 0.0f;
            dt_[r * 6 + 5] = clsf;
            val[r] = okrow ? 1 : 0;
        }
    }
    __syncthreads();

    if (tid < TOPK) {
        const u64 vb = __ballot(val[tid] != 0);
        if (lane == 0) validG[img * 8 + wv] = vb;
    }
}

// ---- k3 iou: full-chip bitmask, boxes staged in LDS ----
__global__ __launch_bounds__(256) void iou_kernel(const float* __restrict__ nmsG,
                                                  u64* __restrict__ maskG) {
    __shared__ float bx1[TOPK], by1[TOPK], bx2[TOPK], by2[TOPK], bar[TOPK];
    const int img = blockIdx.x;
    const int slab = blockIdx.y;            // 32 slabs x 16 rows
    const int tid = threadIdx.x;
    const int lane = tid & 63;
    const float* nb_ = nmsG + (size_t)img * (5 * TOPK);
    for (int i = tid; i < TOPK; i += 256) {
        bx1[i] = nb_[i];            by1[i] = nb_[TOPK + i];
        bx2[i] = nb_[2 * TOPK + i]; by2[i] = nb_[3 * TOPK + i];
        bar[i] = nb_[4 * TOPK + i];
    }
    __syncthreads();
    const int q0 = slab * (16 * TOPK);
    for (int q = q0 + tid; q < q0 + 16 * TOPK; q += 256) {
        const int i = q >> 9;               // wave-uniform -> LDS broadcast
        const int j = q & (TOPK - 1);       // lane-consecutive -> conflict-free
        bool sup = false;
        if (j > i) {
            const float xx1 = fmaxf(bx1[i], bx1[j]);
            const float yy1 = fmaxf(by1[i], by1[j]);
            const float xx2 = fminf(bx2[i], bx2[j]);
            const float yy2 = fminf(by2[i], by2[j]);
            const float iw = fmaxf(xx2 - xx1, 0.0f);
            const float ih = fmaxf(yy2 - yy1, 0.0f);
            const float inter = iw * ih;
            const float uni = bar[i] + bar[j] - inter;
            const float iou = inter / uni;  // IEEE div, NaN>thre == false (matches ref)
            sup = iou > NMS_THRE;
        }
        const u64 bm = __ballot(sup);
        if (lane == 0) maskG[(size_t)img * 4096 + (q >> 6)] = bm;
    }
}

// ---- k4 greedy: sequential NMS with 4-deep LDS prefetch, branchless update ----
__global__ __launch_bounds__(256) void greedy_kernel(const u64* __restrict__ maskG,
                                                     const u64* __restrict__ validG,
                                                     const float* __restrict__ detG,
                                                     float* __restrict__ out) {
    __shared__ u64 m[TOPK * 8];     // 32 KB
    __shared__ u64 kw8[8];
    const int img = blockIdx.x;
    const int tid = threadIdx.x;
    const int lane = tid & 63;
    const int wv = tid >> 6;
    const u64* mg = maskG + (size_t)img * 4096;
    for (int i = tid; i < 4096; i += 256) m[i] = mg[i];
    __syncthreads();

    if (wv == 0) {
        const bool ld = lane < 8;
        u64 kw = ld ? validG[img * 8 + lane] : 0ull;
        u64 p0 = ld ? m[0 * 8 + lane] : 0ull;
        u64 p1 = ld ? m[1 * 8 + lane] : 0ull;
        u64 p2 = ld ? m[2 * 8 + lane] : 0ull;
        u64 p3 = ld ? m[3 * 8 + lane] : 0ull;
        for (int i = 0; i < TOPK; i += 4) {
            {
                const u64 w = __shfl(kw, i >> 6);
                const u64 bit = (w >> (i & 63)) & 1ull;
                kw &= ~(p0 & (0ull - bit));
                p0 = (ld && i + 4 < TOPK) ? m[(i + 4) * 8 + lane] : 0ull;
            }
            {
                const u64 w = __shfl(kw, (i + 1) >> 6);
                const u64 bit = (w >> ((i + 1) & 63)) & 1ull;
                kw &= ~(p1 & (0ull - bit));
                p1 = (ld && i + 5 < TOPK) ? m[(i + 5) * 8 + lane] : 0ull;
            }
            {
                const u64 w = __shfl(kw, (i + 2) >> 6);
                const u64 bit = (w >> ((i + 2) & 63)) & 1ull;
                kw &= ~(p2 & (0ull - bit));
                p2 = (ld && i + 6 < TOPK) ? m[(i + 6) * 8 + lane] : 0ull;
            }
            {
                const u64 w = __shfl(kw, (i + 3) >> 6);
                const u64 bit = (w >> ((i + 3) & 63)) & 1ull;
                kw &= ~(p3 & (0ull - bit));
                p3 = (ld && i + 7 < TOPK) ? m[(i + 7) * 8 + lane] : 0ull;
            }
        }
        if (ld) kw8[lane] = kw;
    }
    __syncthreads();

    const float* dt_ = detG + (size_t)img * (6 * TOPK);
    float* det_out = out + (size_t)img * (TOPK * 6);
    float* keep_out = out + (size_t)BATCH * TOPK * 6 + (size_t)img * TOPK;
    for (int idx = tid; idx < TOPK * 6; idx += 256) {
        const int r = idx / 6;
        const float kf = ((kw8[r >> 6] >> (r & 63)) & 1ull) ? 1.0f : 0.0f;
        det_out[idx] = dt_[idx] * kf;
    }
    for (int r = tid; r < TOPK; r += 256) {
        keep_out[r] = ((kw8[r >> 6] >> (r & 63)) & 1ull) ? 1.0f : 0.0f;
    }
}

extern "C" void kernel_launch(void* const* d_in, const int* in_sizes, int n_in,
                              void* d_out, int out_size, void* d_ws, size_t ws_size,
                              hipStream_t stream) {
    const float* pred = (const float*)d_in[0];
    float* out = (float*)d_out;
    char* ws = (char*)d_ws;
    u64* listG = (u64*)(ws + OFF_LIST);
    u32* cntG = (u32*)(ws + OFF_CNT);
    float* nmsG = (float*)(ws + OFF_NMS);
    float* detG = (float*)(ws + OFF_DET);
    u64* validG = (u64*)(ws + OFF_VALID);
    u64* maskG = (u64*)(ws + OFF_MASK);

    zero_kernel<<<1, 64, 0, stream>>>(cntG);
    scan_kernel<<<(BATCH * NANCH) / 16, 256, 0, stream>>>(pred, listG, cntG);
    select_kernel<<<BATCH, 1024, 0, stream>>>(pred, listG, cntG, nmsG, detG, validG);
    dim3 g4(BATCH, 32);
    iou_kernel<<<g4, 256, 0, stream>>>(nmsG, maskG);
    greedy_kernel<<<BATCH, 256, 0, stream>>>(maskG, validG, detG, out);
}

// Round 5
// 439.051 us; speedup vs baseline: 2.0734x; 2.0734x over previous
//
#include <hip/hip_runtime.h>
#include <stdint.h>

#define BATCH 32
#define NANCH 25200
#define CH 85
#define NCLS 80
#define TOPK 512
#define CONF_THRE 0.7f
#define NMS_THRE 0.45f
#define CLS_OFF 4096.0f

typedef unsigned long long u64;
typedef unsigned int u32;

// ws layout (bytes):
//   [0, 3225600)          u32 conf32[32][25200]    (conf bits, 0 if below threshold)
//   [3225600, +327680)    float nms[32][5][512]    x1,y1,x2,y2,area (class-offset)
//   [3553280, +393216)    float det[32][512][6]
//   [3946496, +2048)      u64 valid[32][8]
//   [3948544, +1048576)   u64 mask[32][512][8]
#define OFF_CONF  0
#define OFF_NMS   3225600
#define OFF_DET   3553280
#define OFF_VALID 3946496
#define OFF_MASK  3948544

// ---- k1 scan: wave-transposed, no LDS, no barriers, NO ATOMICS (r4 lesson:
//      32 contended global counters serialized cross-XCD -> 10x regression) ----
__global__ __launch_bounds__(256) void scan_kernel(const float* __restrict__ pred,
                                                   u32* __restrict__ conf32) {
    const int tid = threadIdx.x;
    const int lane = tid & 63;
    const int wv = tid >> 6;
    const int g = lane >> 4;          // anchor-in-wave 0..3
    const int l = lane & 15;          // lane-in-group
    const int a = blockIdx.x * 16 + wv * 4 + g;     // flat img*NANCH+anchor
    const size_t base = (size_t)a * CH;

    float m = -1.0f, obj = 0.0f;
    {   // p = l*4 .. l*4+3  (covers 0..63)
        const float4 q = *(const float4*)(pred + base + (l << 2));
        const int p = l << 2;
        if (p + 0 >= 5) m = fmaxf(m, q.x); else if (p + 0 == 4) obj = q.x;
        if (p + 1 >= 5) m = fmaxf(m, q.y); else if (p + 1 == 4) obj = q.y;
        if (p + 2 >= 5) m = fmaxf(m, q.z); else if (p + 2 == 4) obj = q.z;
        if (p + 3 >= 5) m = fmaxf(m, q.w); else if (p + 3 == 4) obj = q.w;
    }
    if (l < 5) {                      // p = 64 .. 83 (all classes)
        const float4 q = *(const float4*)(pred + base + 64 + (l << 2));
        m = fmaxf(fmaxf(m, fmaxf(q.x, q.y)), fmaxf(q.z, q.w));
    } else if (l == 5) {              // p = 84
        m = fmaxf(m, pred[base + 84]);
    }
    #pragma unroll
    for (int off = 1; off < 16; off <<= 1) m = fmaxf(m, __shfl_xor(m, off));
    const float ob = __shfl(obj, (lane & 48) + 1);  // lane g*16+1 holds p==4
    const float conf = ob * m;
    if (l == 0)
        conf32[a] = (conf >= CONF_THRE) ? __float_as_uint(conf) : 0u;
}

// ---- k2: fused hist + threshold + compact + rank sort + gather.
//      Dense passes vectorized with uint4 (7 strided iterations, not 25). ----
__global__ __launch_bounds__(1024) void select_kernel(const float* __restrict__ pred,
                                                      const u32* __restrict__ conf32,
                                                      float* __restrict__ nmsG,
                                                      float* __restrict__ detG,
                                                      u64* __restrict__ validG) {
    __shared__ u64 sbuf[1024];
    __shared__ u64 sorted[1024];
    __shared__ u32 hist[256];
    __shared__ u32 wtot[4];
    __shared__ u32 s_cnt, s_pivot;
    __shared__ unsigned char val[TOPK];

    const int img = blockIdx.x;
    const int tid = threadIdx.x;
    const int lane = tid & 63;
    const int wv = tid >> 6;

    if (tid == 0) { s_cnt = 0u; s_pivot = 0u; }   // pivot 0 => T=0x3F000000 selects all valid
    if (tid < 256) hist[tid] = 0u;
    __syncthreads();

    const uint4* cd4 = (const uint4*)(conf32 + (size_t)img * NANCH);   // 6300 vecs

    // pass 1: 256-bin histogram of top-8 mantissa bits (valid bins 102..255)
    for (int i = tid; i < NANCH / 4; i += 1024) {
        const uint4 q = cd4[i];
        if (q.x) atomicAdd(&hist[(q.x >> 15) & 255u], 1u);
        if (q.y) atomicAdd(&hist[(q.y >> 15) & 255u], 1u);
        if (q.z) atomicAdd(&hist[(q.z >> 15) & 255u], 1u);
        if (q.w) atomicAdd(&hist[(q.w >> 15) & 255u], 1u);
    }
    __syncthreads();

    // inclusive suffix scan over 256 bins (4 waves + cross-wave totals)
    u32 v = 0, s = 0;
    if (tid < 256) {
        v = hist[tid]; s = v;
        #pragma unroll
        for (int off = 1; off < 64; off <<= 1) {
            const u32 t = __shfl_down(s, off);
            if (lane + off < 64) s += t;
        }
        if (lane == 0) wtot[wv] = s;
    }
    __syncthreads();
    if (tid < 256) {
        u32 add = 0;
        for (int w2 = wv + 1; w2 < 4; ++w2) add += wtot[w2];
        const u32 sfull = s + add;        // count in bins >= tid
        const u32 snext = sfull - v;      // count in bins >  tid
        if (sfull >= TOPK && snext < TOPK) s_pivot = (u32)tid;
    }
    __syncthreads();
    const u32 T = 0x3F000000u | (s_pivot << 15);

    // pass 2 (L2-hot): compact conf >= T (order-free; rank sort restores exact order)
    for (int i = tid; i < NANCH / 4; i += 1024) {
        const uint4 q = cd4[i];
        const u32 a0 = (u32)(i << 2);
        if (q.x >= T) { const u32 p = atomicAdd(&s_cnt, 1u);
            if (p < 1024u) sbuf[p] = ((u64)q.x << 32) | (u64)(0xFFFFFFFFu - a0); }
        if (q.y >= T) { const u32 p = atomicAdd(&s_cnt, 1u);
            if (p < 1024u) sbuf[p] = ((u64)q.y << 32) | (u64)(0xFFFFFFFFu - (a0 + 1)); }
        if (q.z >= T) { const u32 p = atomicAdd(&s_cnt, 1u);
            if (p < 1024u) sbuf[p] = ((u64)q.z << 32) | (u64)(0xFFFFFFFFu - (a0 + 2)); }
        if (q.w >= T) { const u32 p = atomicAdd(&s_cnt, 1u);
            if (p < 1024u) sbuf[p] = ((u64)q.w << 32) | (u64)(0xFFFFFFFFu - (a0 + 3)); }
    }
    __syncthreads();
    const u32 mc = (s_cnt > 1024u) ? 1024u : s_cnt;

    // rank sort (keys unique by anchor): rank = #{key' > key}
    sorted[tid] = 0ull;
    u32 rank = 0; u64 my = 0ull;
    if (tid < (int)mc) {
        my = sbuf[tid];
        for (u32 i = 0; i < mc; ++i) rank += (sbuf[i] > my) ? 1u : 0u;
    }
    __syncthreads();
    if (tid < (int)mc && rank < 1024u) sorted[rank] = my;
    __syncthreads();

    // gather: 8 rows per wave via 8-lane groups; 4 sequential batches of 128 rows.
    // lane l covers classes {l, 8+l, ..., 72+l}; argmax first-max tie rule.
    const int g = lane >> 3;          // row-in-wave 0..7
    const int l = lane & 7;           // lane-in-group
    float* nb_ = nmsG + (size_t)img * (5 * TOPK);
    float* dt_ = detG + (size_t)img * (6 * TOPK);
    for (int pass = 0; pass < 4; ++pass) {
        const int r = pass * 128 + wv * 8 + g;
        const u64 key = sorted[r];
        const float conf = __uint_as_float((u32)(key >> 32));
        const bool okrow = conf >= CONF_THRE;
        float x1 = 0.f, y1 = 0.f, x2 = 0.f, y2 = 0.f, clsf = 0.f;
        if (okrow) {
            const u32 anchor = 0xFFFFFFFFu - (u32)(key & 0xFFFFFFFFull);
            const float* row = pred + ((size_t)img * NANCH + anchor) * CH;
            // 10 independent strided loads + box load, all issued together
            float vs[10];
            #pragma unroll
            for (int k = 0; k < 10; ++k) vs[k] = row[5 + l + 8 * k];
            float4 box;
            if (l == 0) box = *(const float4*)row;
            float vv = vs[0];
            int ci = l;
            #pragma unroll
            for (int k = 1; k < 10; ++k)
                if (vs[k] > vv) { vv = vs[k]; ci = 8 * k + l; }   // strict > keeps lowest idx
            // reduce within 8-lane group: larger value wins; tie -> lower class idx
            #pragma unroll
            for (int off = 4; off > 0; off >>= 1) {
                const float ov = __shfl_xor(vv, off);
                const int oi = __shfl_xor(ci, off);
                if (ov > vv || (ov == vv && oi < ci)) { vv = ov; ci = oi; }
            }
            if (l == 0) {
                const float hw = box.z * 0.5f, hh = box.w * 0.5f;
                x1 = box.x - hw; y1 = box.y - hh; x2 = box.x + hw; y2 = box.y + hh;
                clsf = (float)ci;
            }
        }
        if (l == 0) {
            const float off = clsf * CLS_OFF;
            const float X1 = x1 + off, Y1 = y1 + off, X2 = x2 + off, Y2 = y2 + off;
            nb_[0 * TOPK + r] = X1; nb_[1 * TOPK + r] = Y1;
            nb_[2 * TOPK + r] = X2; nb_[3 * TOPK + r] = Y2;
            nb_[4 * TOPK + r] = (X2 - X1) * (Y2 - Y1);
            dt_[r * 6 + 0] = x1; dt_[r * 6 + 1] = y1;
            dt_[r * 6 + 2] = x2; dt_[r * 6 + 3] = y2;
            dt_[r * 6 + 4] = okrow ? conf : 0.0f;
            dt_[r * 6 + 5] = clsf;
            val[r] = okrow ? 1 : 0;
        }
    }
    __syncthreads();

    if (tid < TOPK) {
        const u64 vb = __ballot(val[tid] != 0);
        if (lane == 0) validG[img * 8 + wv] = vb;
    }
}

// ---- k3 iou: full-chip bitmask, boxes staged in LDS ----
__global__ __launch_bounds__(256) void iou_kernel(const float* __restrict__ nmsG,
                                                  u64* __restrict__ maskG) {
    __shared__ float bx1[TOPK], by1[TOPK], bx2[TOPK], by2[TOPK], bar[TOPK];
    const int img = blockIdx.x;
    const int slab = blockIdx.y;            // 32 slabs x 16 rows
    const int tid = threadIdx.x;
    const int lane = tid & 63;
    const float* nb_ = nmsG + (size_t)img * (5 * TOPK);
    for (int i = tid; i < TOPK; i += 256) {
        bx1[i] = nb_[i];            by1[i] = nb_[TOPK + i];
        bx2[i] = nb_[2 * TOPK + i]; by2[i] = nb_[3 * TOPK + i];
        bar[i] = nb_[4 * TOPK + i];
    }
    __syncthreads();
    const int q0 = slab * (16 * TOPK);
    for (int q = q0 + tid; q < q0 + 16 * TOPK; q += 256) {
        const int i = q >> 9;               // wave-uniform -> LDS broadcast
        const int j = q & (TOPK - 1);       // lane-consecutive -> conflict-free
        bool sup = false;
        if (j > i) {
            const float xx1 = fmaxf(bx1[i], bx1[j]);
            const float yy1 = fmaxf(by1[i], by1[j]);
            const float xx2 = fminf(bx2[i], bx2[j]);
            const float yy2 = fminf(by2[i], by2[j]);
            const float iw = fmaxf(xx2 - xx1, 0.0f);
            const float ih = fmaxf(yy2 - yy1, 0.0f);
            const float inter = iw * ih;
            const float uni = bar[i] + bar[j] - inter;
            const float iou = inter / uni;  // IEEE div, NaN>thre == false (matches ref)
            sup = iou > NMS_THRE;
        }
        const u64 bm = __ballot(sup);
        if (lane == 0) maskG[(size_t)img * 4096 + (q >> 6)] = bm;
    }
}

// ---- k4 greedy: sequential NMS with 4-deep LDS prefetch, branchless update ----
__global__ __launch_bounds__(256) void greedy_kernel(const u64* __restrict__ maskG,
                                                     const u64* __restrict__ validG,
                                                     const float* __restrict__ detG,
                                                     float* __restrict__ out) {
    __shared__ u64 m[TOPK * 8];     // 32 KB
    __shared__ u64 kw8[8];
    const int img = blockIdx.x;
    const int tid = threadIdx.x;
    const int lane = tid & 63;
    const int wv = tid >> 6;
    const u64* mg = maskG + (size_t)img * 4096;
    for (int i = tid; i < 4096; i += 256) m[i] = mg[i];
    __syncthreads();

    if (wv == 0) {
        const bool ld = lane < 8;
        u64 kw = ld ? validG[img * 8 + lane] : 0ull;
        u64 p0 = ld ? m[0 * 8 + lane] : 0ull;
        u64 p1 = ld ? m[1 * 8 + lane] : 0ull;
        u64 p2 = ld ? m[2 * 8 + lane] : 0ull;
        u64 p3 = ld ? m[3 * 8 + lane] : 0ull;
        for (int i = 0; i < TOPK; i += 4) {
            {
                const u64 w = __shfl(kw, i >> 6);
                const u64 bit = (w >> (i & 63)) & 1ull;
                kw &= ~(p0 & (0ull - bit));
                p0 = (ld && i + 4 < TOPK) ? m[(i + 4) * 8 + lane] : 0ull;
            }
            {
                const u64 w = __shfl(kw, (i + 1) >> 6);
                const u64 bit = (w >> ((i + 1) & 63)) & 1ull;
                kw &= ~(p1 & (0ull - bit));
                p1 = (ld && i + 5 < TOPK) ? m[(i + 5) * 8 + lane] : 0ull;
            }
            {
                const u64 w = __shfl(kw, (i + 2) >> 6);
                const u64 bit = (w >> ((i + 2) & 63)) & 1ull;
                kw &= ~(p2 & (0ull - bit));
                p2 = (ld && i + 6 < TOPK) ? m[(i + 6) * 8 + lane] : 0ull;
            }
            {
                const u64 w = __shfl(kw, (i + 3) >> 6);
                const u64 bit = (w >> ((i + 3) & 63)) & 1ull;
                kw &= ~(p3 & (0ull - bit));
                p3 = (ld && i + 7 < TOPK) ? m[(i + 7) * 8 + lane] : 0ull;
            }
        }
        if (ld) kw8[lane] = kw;
    }
    __syncthreads();

    const float* dt_ = detG + (size_t)img * (6 * TOPK);
    float* det_out = out + (size_t)img * (TOPK * 6);
    float* keep_out = out + (size_t)BATCH * TOPK * 6 + (size_t)img * TOPK;
    for (int idx = tid; idx < TOPK * 6; idx += 256) {
        const int r = idx / 6;
        const float kf = ((kw8[r >> 6] >> (r & 63)) & 1ull) ? 1.0f : 0.0f;
        det_out[idx] = dt_[idx] * kf;
    }
    for (int r = tid; r < TOPK; r += 256) {
        keep_out[r] = ((kw8[r >> 6] >> (r & 63)) & 1ull) ? 1.0f : 0.0f;
    }
}

extern "C" void kernel_launch(void* const* d_in, const int* in_sizes, int n_in,
                              void* d_out, int out_size, void* d_ws, size_t ws_size,
                              hipStream_t stream) {
    const float* pred = (const float*)d_in[0];
    float* out = (float*)d_out;
    char* ws = (char*)d_ws;
    u32* conf32 = (u32*)(ws + OFF_CONF);
    float* nmsG = (float*)(ws + OFF_NMS);
    float* detG = (float*)(ws + OFF_DET);
    u64* validG = (u64*)(ws + OFF_VALID);
    u64* maskG = (u64*)(ws + OFF_MASK);

    scan_kernel<<<(BATCH * NANCH) / 16, 256, 0, stream>>>(pred, conf32);
    select_kernel<<<BATCH, 1024, 0, stream>>>(pred, conf32, nmsG, detG, validG);
    dim3 g4(BATCH, 32);
    iou_kernel<<<g4, 256, 0, stream>>>(nmsG, maskG);
    greedy_kernel<<<BATCH, 256, 0, stream>>>(maskG, validG, detG, out);
}